// Round 1
// baseline (542.965 us; speedup 1.0000x reference)
//
#include <hip/hip_runtime.h>
#include <hip/hip_bf16.h>
#include <stdint.h>

// ---------------------------------------------------------------------------
// BaseAttentionBlock: x[8,512,64,64] -> out[8,512,64,64]
//   value = wv@x + bv                        [B,256,N]
//   k     = relu(BN(wk@x + bk))              [B,256,N]   (query == key)
//   sim   = softmax(k^T k / 16, axis=-1)     [B,N,N]  (never materialized)
//   ctx   = sim @ value^T                    [B,256,N]
//   out   = wW@ctx + bW                      [B,512,N]
// All GEMMs on bf16 MFMA (16x16x32). Flash-style attention, online softmax.
// MFMA frag layout (gfx950): A[row=l&15][k=(l>>4)*8+j], B[col=l&15][k=(l>>4)*8+j],
//                            D[row=(l>>4)*4+r][col=l&15].
// ---------------------------------------------------------------------------

typedef __bf16 bf16;
typedef bf16 bf16x4 __attribute__((ext_vector_type(4)));
typedef bf16 bf16x8 __attribute__((ext_vector_type(8)));
typedef float f32x4 __attribute__((ext_vector_type(4)));

#define Bb 8
#define Cc 512
#define Nn 4096
#define Kc 256
#define Vv 256
#define Oo 512
#define BN_EPS 1e-5f

static __device__ __forceinline__ f32x4 mfma16(bf16x8 a, bf16x8 b, f32x4 c) {
    return __builtin_amdgcn_mfma_f32_16x16x32_bf16(a, b, c, 0, 0, 0);
}

// ---------------- prep: fold BN into wk, cast weights to bf16 ---------------
__global__ __launch_bounds__(256) void prep_kernel(
        const float* __restrict__ wk, const float* __restrict__ wv,
        const float* __restrict__ wW, const float* __restrict__ bk,
        const float* __restrict__ gamma, const float* __restrict__ beta,
        const float* __restrict__ rmean, const float* __restrict__ rvar,
        bf16* __restrict__ wkv, bf16* __restrict__ wWb, float* __restrict__ shift2) {
    int idx = blockIdx.x * 256 + threadIdx.x;
    if (idx < 131072) {                      // wk rows 0..255 with BN scale folded
        int kc = idx >> 9;
        float sc = gamma[kc] * rsqrtf(rvar[kc] + BN_EPS);
        wkv[idx] = (bf16)(wk[idx] * sc);
    } else if (idx < 262144) {               // wv rows 256..511
        wkv[idx] = (bf16)(wv[idx - 131072]);
    } else if (idx < 393216) {
        int j = idx - 262144;
        wWb[j] = (bf16)(wW[j]);
    } else if (idx < 393472) {
        int kc = idx - 393216;
        float sc = gamma[kc] * rsqrtf(rvar[kc] + BN_EPS);
        shift2[kc] = (bk[kc] - rmean[kc]) * sc + beta[kc];
    }
}

// ---------------- transpose: x[b,c,n] f32 -> xT[b,n,c] bf16 -----------------
__global__ __launch_bounds__(256) void transpose_kernel(
        const float* __restrict__ x, bf16* __restrict__ xT) {
    int b = blockIdx.z, c0 = blockIdx.y * 32, n0 = blockIdx.x * 64;
    __shared__ float lds[32][65];
    int t = threadIdx.x;
    int r = t >> 3, s = t & 7;               // c-row, 8-float segment
    const float* src = x + ((size_t)(b * Cc + c0 + r)) * Nn + n0 + s * 8;
    float4 v0 = *(const float4*)src;
    float4 v1 = *(const float4*)(src + 4);
    lds[r][s * 8 + 0] = v0.x; lds[r][s * 8 + 1] = v0.y;
    lds[r][s * 8 + 2] = v0.z; lds[r][s * 8 + 3] = v0.w;
    lds[r][s * 8 + 4] = v1.x; lds[r][s * 8 + 5] = v1.y;
    lds[r][s * 8 + 6] = v1.z; lds[r][s * 8 + 7] = v1.w;
    __syncthreads();
    int wr = t >> 2, part = t & 3;           // n-row, 8-channel segment
    bf16x8 o;
#pragma unroll
    for (int j = 0; j < 8; ++j) o[j] = (bf16)lds[part * 8 + j][wr];
    *(bf16x8*)(xT + ((size_t)(b * Nn + n0 + wr)) * Cc + c0 + part * 8) = o;
}

// ------- proj: kT[b,n,kc]=relu(BN(wk@x+bk)), val[b,v,n]=wv@x+bv  ------------
__global__ __launch_bounds__(256) void proj_kernel(
        const bf16* __restrict__ xT, const bf16* __restrict__ wkv,
        const float* __restrict__ shift2, const float* __restrict__ bv,
        bf16* __restrict__ kT, bf16* __restrict__ val) {
    int b = blockIdx.y;
    int w = threadIdx.x >> 6, l = threadIdx.x & 63, g = l >> 4, i = l & 15;
    int n = blockIdx.x * 64 + w * 16 + i;
    const bf16* xrow = xT + ((size_t)(b * Nn + n)) * Cc;
    bf16x8 bf[16];
#pragma unroll
    for (int kk = 0; kk < 16; ++kk) bf[kk] = *(const bf16x8*)(xrow + g * 8 + kk * 32);
    for (int oc = 0; oc < 32; ++oc) {
        f32x4 acc = {0.f, 0.f, 0.f, 0.f};
        const bf16* arow = wkv + (size_t)(oc * 16 + i) * Cc;
#pragma unroll
        for (int kk = 0; kk < 16; ++kk) {
            bf16x8 a = *(const bf16x8*)(arow + g * 8 + kk * 32);
            acc = mfma16(a, bf[kk], acc);
        }
        if (oc < 16) {                       // key channels: BN shift + relu
            int kc0 = oc * 16 + g * 4;
            bf16x4 ov;
#pragma unroll
            for (int r2 = 0; r2 < 4; ++r2) {
                float v = acc[r2] + shift2[kc0 + r2];
                ov[r2] = (bf16)fmaxf(v, 0.f);
            }
            *(bf16x4*)(kT + ((size_t)(b * Nn + n)) * Kc + kc0) = ov;
        } else {                             // value channels
            int vc0 = (oc - 16) * 16 + g * 4;
#pragma unroll
            for (int r2 = 0; r2 < 4; ++r2) {
                float v = acc[r2] + bv[vc0 + r2];
                val[((size_t)(b * Vv + vc0 + r2)) * Nn + n] = (bf16)v;
            }
        }
    }
}

// ---------------- flash attention: ctxT[b,n,v] ------------------------------
__global__ __launch_bounds__(256) void flash_kernel(
        const bf16* __restrict__ kT, const bf16* __restrict__ val,
        bf16* __restrict__ ctxT) {
    __shared__ __align__(16) char ldsK[32 * 512];   // [32 m][256 c] bf16, XOR-swizzled
    __shared__ __align__(16) char ldsV[256 * 64];   // [256 v][32 m] bf16
    __shared__ __align__(16) char ldsP[4 * 16 * 80];// per-wave [16 n][32 m] bf16, rows padded to 80B
    int b = blockIdx.y;
    int t = threadIdx.x;
    int w = t >> 6, l = t & 63, g = l >> 4, i = l & 15;
    int n = blockIdx.x * 64 + w * 16 + i;

    // Q fragments (loop-invariant): kT row n, 256 channels
    const bf16* qrow = kT + ((size_t)(b * Nn + n)) * Kc;
    bf16x8 qf[8];
#pragma unroll
    for (int kk = 0; kk < 8; ++kk) qf[kk] = *(const bf16x8*)(qrow + g * 8 + kk * 32);

    f32x4 ctx[16];
#pragma unroll
    for (int vc = 0; vc < 16; ++vc) ctx[vc] = {0.f, 0.f, 0.f, 0.f};
    float M = -3.0e38f, L = 0.f;

    int srow = t >> 3;                 // K staging: row 0..31
    int scol = (t & 7) * 4;            // 4 x 16B chunks
    const bf16* kbase = kT + ((size_t)b * Nn) * Kc;
    const bf16* vbase = val + ((size_t)(b * Vv + t)) * Nn;  // one v-row per thread
    char* pmy = ldsP + w * 1280 + i * 80;
    int swz = (i & 7) << 4;

    for (int mb = 0; mb < Nn; mb += 32) {
        __syncthreads();
        // stage K tile [mb..mb+32) x 256, XOR-swizzle bits 4..6 by row
        {
            const bf16* ksrc = kbase + ((size_t)(mb + srow)) * Kc + scol * 8;
#pragma unroll
            for (int c = 0; c < 4; ++c) {
                bf16x8 vK = *(const bf16x8*)(ksrc + c * 8);
                int byte = (srow * 512 + (scol + c) * 16) ^ ((srow & 7) << 4);
                *(bf16x8*)(ldsK + byte) = vK;
            }
        }
        // stage V tile [256 v][mb..mb+32)
#pragma unroll
        for (int c = 0; c < 4; ++c) {
            bf16x8 vV = *(const bf16x8*)(vbase + mb + c * 8);
            *(bf16x8*)(ldsV + t * 64 + c * 16) = vV;
        }
        __syncthreads();

        // S^T tiles: D[m][n] = sum_c K[m,c] Q[n,c]  (swapped -> n = lane&15)
        f32x4 s0 = {0.f, 0.f, 0.f, 0.f}, s1 = {0.f, 0.f, 0.f, 0.f};
#pragma unroll
        for (int kk = 0; kk < 8; ++kk) {
            int cb = g * 16 + kk * 64;
            bf16x8 a0 = *(const bf16x8*)(ldsK + ((i * 512 + cb) ^ swz));
            bf16x8 a1 = *(const bf16x8*)(ldsK + (((i + 16) * 512 + cb) ^ swz));
            s0 = mfma16(a0, qf[kk], s0);
            s1 = mfma16(a1, qf[kk], s1);
        }
        // online softmax over m (rows); lane holds m = {4g+r, 16+4g+r}, n = i
        float tmax = -3.0e38f;
#pragma unroll
        for (int r = 0; r < 4; ++r) {
            s0[r] *= 0.0625f; s1[r] *= 0.0625f;
            tmax = fmaxf(tmax, fmaxf(s0[r], s1[r]));
        }
        tmax = fmaxf(tmax, __shfl_xor(tmax, 16, 64));
        tmax = fmaxf(tmax, __shfl_xor(tmax, 32, 64));
        float newM = fmaxf(M, tmax);
        float alpha = __expf(M - newM);
        float p0[4], p1[4], tsum = 0.f;
#pragma unroll
        for (int r = 0; r < 4; ++r) {
            p0[r] = __expf(s0[r] - newM);
            p1[r] = __expf(s1[r] - newM);
            tsum += p0[r] + p1[r];
        }
        tsum += __shfl_xor(tsum, 16, 64);
        tsum += __shfl_xor(tsum, 32, 64);
        L = L * alpha + tsum;
        M = newM;
        // write P tile (per-wave LDS), re-layout for PV B-fragment
        bf16x4 pk0, pk1;
#pragma unroll
        for (int r = 0; r < 4; ++r) { pk0[r] = (bf16)p0[r]; pk1[r] = (bf16)p1[r]; }
        *(bf16x4*)(pmy + g * 8) = pk0;
        *(bf16x4*)(pmy + 32 + g * 8) = pk1;
        // rescale ctx accumulators (n = lane&15 -> alpha lane-uniform)
#pragma unroll
        for (int vc = 0; vc < 16; ++vc) ctx[vc] = ctx[vc] * alpha;
        bf16x8 pb = *(const bf16x8*)(pmy + g * 16);
        // PV: ctxT[v][n] += sum_m V[v,m] P[m,n]
#pragma unroll
        for (int vc = 0; vc < 16; ++vc) {
            bf16x8 av = *(const bf16x8*)(ldsV + (vc * 16 + i) * 64 + g * 16);
            ctx[vc] = mfma16(av, pb, ctx[vc]);
        }
    }
    // epilogue: divide by softmax denom, store ctxT[b,n,v] bf16
    float inv = 1.0f / L;
    bf16* crow = ctxT + ((size_t)(b * Nn + n)) * Vv;
#pragma unroll
    for (int vc = 0; vc < 16; ++vc) {
        bf16x4 o;
#pragma unroll
        for (int r = 0; r < 4; ++r) o[r] = (bf16)(ctx[vc][r] * inv);
        *(bf16x4*)(crow + vc * 16 + g * 4) = o;
    }
}

// ---------------- out: wW @ ctx + bW, f32 -----------------------------------
__global__ __launch_bounds__(256) void out_kernel(
        const bf16* __restrict__ ctxT, const bf16* __restrict__ wWb,
        const float* __restrict__ bW, float* __restrict__ out) {
    int b = blockIdx.y;
    int w = threadIdx.x >> 6, l = threadIdx.x & 63, g = l >> 4, i = l & 15;
    int n = blockIdx.x * 64 + w * 16 + i;
    const bf16* crow = ctxT + ((size_t)(b * Nn + n)) * Vv;
    bf16x8 bfr[8];
#pragma unroll
    for (int kk = 0; kk < 8; ++kk) bfr[kk] = *(const bf16x8*)(crow + g * 8 + kk * 32);
    for (int oc = 0; oc < 32; ++oc) {
        f32x4 acc = {0.f, 0.f, 0.f, 0.f};
        const bf16* arow = wWb + (size_t)(oc * 16 + i) * Vv;
#pragma unroll
        for (int kk = 0; kk < 8; ++kk)
            acc = mfma16(*(const bf16x8*)(arow + g * 8 + kk * 32), bfr[kk], acc);
        int o0 = oc * 16 + g * 4;
#pragma unroll
        for (int r = 0; r < 4; ++r)
            out[((size_t)(b * Oo + o0 + r)) * Nn + n] = acc[r] + bW[o0 + r];
    }
}

// ---------------------------------------------------------------------------
extern "C" void kernel_launch(void* const* d_in, const int* in_sizes, int n_in,
                              void* d_out, int out_size, void* d_ws, size_t ws_size,
                              hipStream_t stream) {
    const float* x     = (const float*)d_in[0];
    const float* wv    = (const float*)d_in[1];
    const float* bv    = (const float*)d_in[2];
    const float* wk    = (const float*)d_in[3];
    const float* bk    = (const float*)d_in[4];
    const float* gamma = (const float*)d_in[5];
    const float* beta  = (const float*)d_in[6];
    const float* rmean = (const float*)d_in[7];
    const float* rvar  = (const float*)d_in[8];
    const float* wW    = (const float*)d_in[9];
    const float* bW    = (const float*)d_in[10];
    float* out = (float*)d_out;

    char* ws = (char*)d_ws;
    bf16*  xT     = (bf16*)(ws + 0);          // 8*4096*512*2  = 32 MiB
    bf16*  kTp    = (bf16*)(ws + 33554432);   // 8*4096*256*2  = 16 MiB
    bf16*  valp   = (bf16*)(ws + 50331648);   // 8*256*4096*2  = 16 MiB
    bf16*  ctxT   = (bf16*)(ws + 67108864);   // 8*4096*256*2  = 16 MiB
    bf16*  wkv    = (bf16*)(ws + 83886080);   // 512*512*2     = 512 KiB
    bf16*  wWb    = (bf16*)(ws + 84410368);   // 512*256*2     = 256 KiB
    float* shift2 = (float*)(ws + 84672512);  // 256*4

    prep_kernel<<<dim3(1537), dim3(256), 0, stream>>>(wk, wv, wW, bk, gamma, beta,
                                                      rmean, rvar, wkv, wWb, shift2);
    transpose_kernel<<<dim3(64, 16, 8), dim3(256), 0, stream>>>(x, xT);
    proj_kernel<<<dim3(64, 8), dim3(256), 0, stream>>>(xT, wkv, shift2, bv, kTp, valp);
    flash_kernel<<<dim3(64, 8), dim3(256), 0, stream>>>(kTp, valp, ctxT);
    out_kernel<<<dim3(64, 8), dim3(256), 0, stream>>>(ctxT, wWb, bW, out);
}

// Round 2
// 472.785 us; speedup vs baseline: 1.1484x; 1.1484x over previous
//
#include <hip/hip_runtime.h>
#include <hip/hip_bf16.h>
#include <stdint.h>

// ---------------------------------------------------------------------------
// BaseAttentionBlock: x[8,512,64,64] -> out[8,512,64,64]
//   value = wv@x + bv; k = relu(BN(wk@x+bk)); sim = softmax(kT k /16);
//   ctx = sim @ value^T; out = wW@ctx + bW
// Flash attention on mfma_f32_32x32x16_bf16, q=32/wave, 2-wave blocks.
// kT is pre-scaled by sqrt(1/16 * log2(e)) so softmax runs in exp2 domain.
// ---------------------------------------------------------------------------

typedef __bf16 bf16;
typedef bf16 bf16x4 __attribute__((ext_vector_type(4)));
typedef bf16 bf16x8 __attribute__((ext_vector_type(8)));
typedef float f32x4 __attribute__((ext_vector_type(4)));
typedef float f32x16 __attribute__((ext_vector_type(16)));

#define Bb 8
#define Cc 512
#define Nn 4096
#define Kc 256
#define Vv 256
#define Oo 512
#define BN_EPS 1e-5f
#define QSCALE 0.300280601f   // sqrt(0.0625 * log2(e)); applied to kT per side

static __device__ __forceinline__ f32x4 mfma16(bf16x8 a, bf16x8 b, f32x4 c) {
    return __builtin_amdgcn_mfma_f32_16x16x32_bf16(a, b, c, 0, 0, 0);
}
static __device__ __forceinline__ f32x16 mfma32(bf16x8 a, bf16x8 b, f32x16 c) {
    return __builtin_amdgcn_mfma_f32_32x32x16_bf16(a, b, c, 0, 0, 0);
}
static __device__ __forceinline__ unsigned cvtpk(float lo, float hi) {
    unsigned r;
    asm("v_cvt_pk_bf16_f32 %0, %1, %2" : "=v"(r) : "v"(lo), "v"(hi));
    return r;
}
#define GLD16(gp, lp) __builtin_amdgcn_global_load_lds( \
    (const __attribute__((address_space(1))) unsigned int*)(gp), \
    (__attribute__((address_space(3))) unsigned int*)(lp), 16, 0, 0)

// ---------------- prep: fold BN into wk, cast weights to bf16 ---------------
__global__ __launch_bounds__(256) void prep_kernel(
        const float* __restrict__ wk, const float* __restrict__ wv,
        const float* __restrict__ wW, const float* __restrict__ bk,
        const float* __restrict__ gamma, const float* __restrict__ beta,
        const float* __restrict__ rmean, const float* __restrict__ rvar,
        bf16* __restrict__ wkv, bf16* __restrict__ wWb, float* __restrict__ shift2) {
    int idx = blockIdx.x * 256 + threadIdx.x;
    if (idx < 131072) {                      // wk rows 0..255 with BN scale folded
        int kc = idx >> 9;
        float sc = gamma[kc] * rsqrtf(rvar[kc] + BN_EPS);
        wkv[idx] = (bf16)(wk[idx] * sc);
    } else if (idx < 262144) {               // wv rows 256..511
        wkv[idx] = (bf16)(wv[idx - 131072]);
    } else if (idx < 393216) {
        int j = idx - 262144;
        wWb[j] = (bf16)(wW[j]);
    } else if (idx < 393472) {
        int kc = idx - 393216;
        float sc = gamma[kc] * rsqrtf(rvar[kc] + BN_EPS);
        shift2[kc] = (bk[kc] - rmean[kc]) * sc + beta[kc];
    }
}

// ---------------- transpose: x[b,c,n] f32 -> xT[b,n,c] bf16 -----------------
__global__ __launch_bounds__(256) void transpose_kernel(
        const float* __restrict__ x, bf16* __restrict__ xT) {
    int b = blockIdx.z, c0 = blockIdx.y * 32, n0 = blockIdx.x * 64;
    __shared__ float lds[32][65];
    int t = threadIdx.x;
    int r = t >> 3, s = t & 7;
    const float* src = x + ((size_t)(b * Cc + c0 + r)) * Nn + n0 + s * 8;
    float4 v0 = *(const float4*)src;
    float4 v1 = *(const float4*)(src + 4);
    lds[r][s * 8 + 0] = v0.x; lds[r][s * 8 + 1] = v0.y;
    lds[r][s * 8 + 2] = v0.z; lds[r][s * 8 + 3] = v0.w;
    lds[r][s * 8 + 4] = v1.x; lds[r][s * 8 + 5] = v1.y;
    lds[r][s * 8 + 6] = v1.z; lds[r][s * 8 + 7] = v1.w;
    __syncthreads();
    int wr = t >> 2, part = t & 3;
    bf16x8 o;
#pragma unroll
    for (int j = 0; j < 8; ++j) o[j] = (bf16)lds[part * 8 + j][wr];
    *(bf16x8*)(xT + ((size_t)(b * Nn + n0 + wr)) * Cc + c0 + part * 8) = o;
}

// ------- proj: kT[b,n,kc]=relu(BN(wk@x+bk))*QSCALE, val[b,v,n]=wv@x+bv ------
__global__ __launch_bounds__(256) void proj_kernel(
        const bf16* __restrict__ xT, const bf16* __restrict__ wkv,
        const float* __restrict__ shift2, const float* __restrict__ bv,
        bf16* __restrict__ kT, bf16* __restrict__ val) {
    int b = blockIdx.y;
    int w = threadIdx.x >> 6, l = threadIdx.x & 63, g = l >> 4, i = l & 15;
    int n = blockIdx.x * 64 + w * 16 + i;
    const bf16* xrow = xT + ((size_t)(b * Nn + n)) * Cc;
    bf16x8 bf[16];
#pragma unroll
    for (int kk = 0; kk < 16; ++kk) bf[kk] = *(const bf16x8*)(xrow + g * 8 + kk * 32);
    for (int oc = 0; oc < 32; ++oc) {
        f32x4 acc = {0.f, 0.f, 0.f, 0.f};
        const bf16* arow = wkv + (size_t)(oc * 16 + i) * Cc;
#pragma unroll
        for (int kk = 0; kk < 16; ++kk) {
            bf16x8 a = *(const bf16x8*)(arow + g * 8 + kk * 32);
            acc = mfma16(a, bf[kk], acc);
        }
        if (oc < 16) {                       // key channels: BN shift + relu + qscale
            int kc0 = oc * 16 + g * 4;
            bf16x4 ov;
#pragma unroll
            for (int r2 = 0; r2 < 4; ++r2) {
                float v = acc[r2] + shift2[kc0 + r2];
                ov[r2] = (bf16)(fmaxf(v, 0.f) * QSCALE);
            }
            *(bf16x4*)(kT + ((size_t)(b * Nn + n)) * Kc + kc0) = ov;
        } else {                             // value channels
            int vc0 = (oc - 16) * 16 + g * 4;
#pragma unroll
            for (int r2 = 0; r2 < 4; ++r2) {
                float v = acc[r2] + bv[vc0 + r2];
                val[((size_t)(b * Vv + vc0 + r2)) * Nn + n] = (bf16)v;
            }
        }
    }
}

// ---------------- flash attention: ctxT[b,n,v] ------------------------------
// 128 threads = 2 waves, each wave owns 32 q-rows. KV tile M=32, double-buffered.
// LDS per buffer: K 16KB (XOR-swizzled via pre-permuted global src), V 16KB
// as [4 mg][256 v][8 m]. All staging via global_load_lds (linear LDS dest).
__global__ __launch_bounds__(128, 1) void flash_kernel(
        const bf16* __restrict__ kT, const bf16* __restrict__ val,
        bf16* __restrict__ ctxT) {
    __shared__ __align__(16) char lds[65536];     // 2 x (16KB K + 16KB V)
    int b = blockIdx.x;                           // batch -> XCD (linear%8 == b)
    int t = threadIdx.x;
    int w = t >> 6, l = t & 63;
    int li = l & 31, hi = l >> 5;
    int n = blockIdx.y * 64 + w * 32 + li;

    const bf16* kTb  = kT  + (size_t)b * Nn * Kc;
    const bf16* valb = val + (size_t)b * Vv * Nn;

    // Q fragments (B operand): Q[col n][k = cs*16 + hi*8 + j]
    const bf16* qrow = kTb + (size_t)n * Kc;
    bf16x8 qf[16];
#pragma unroll
    for (int cs = 0; cs < 16; ++cs) qf[cs] = *(const bf16x8*)(qrow + cs * 16 + hi * 8);

    // staging offsets (element units), loop-invariant
    int koff[8], voff[8];
#pragma unroll
    for (int j = 0; j < 8; ++j) {
        int row = w * 16 + j * 2 + hi;            // K tile row this lane stages
        int slotx = li ^ row;                     // inverse of read-side XOR swizzle
        koff[j] = row * 256 + slotx * 8;
        int v = (j & 3) * 64 + l;                 // V chunk: plane = w*2 + (j>>2)
        voff[j] = v * Nn + (w * 2 + (j >> 2)) * 8;
    }
    char* kdst0 = lds + w * 8192;
    char* vdst0 = lds + 16384 + w * 8192;

    f32x16 ctx[8];
#pragma unroll
    for (int vc = 0; vc < 8; ++vc)
#pragma unroll
        for (int r = 0; r < 16; ++r) ctx[vc][r] = 0.f;
    float M = -1.0e30f, L = 0.f;

    // prologue: stage tile 0 into buffer 0
#pragma unroll
    for (int j = 0; j < 8; ++j) {
        GLD16(kTb + koff[j], kdst0 + j * 1024);
        GLD16(valb + voff[j], vdst0 + j * 1024);
    }
    __syncthreads();

    for (int it = 0; it < Nn / 32; ++it) {
        int buf = it & 1;
        if (it + 1 < Nn / 32) {                   // stage next tile (other buffer)
            int smb = (it + 1) * 32;
            char* kd = kdst0 + (buf ^ 1) * 32768;
            char* vd = vdst0 + (buf ^ 1) * 32768;
            const bf16* kg = kTb + smb * 256;
            const bf16* vg = valb + smb;
#pragma unroll
            for (int j = 0; j < 8; ++j) {
                GLD16(kg + koff[j], kd + j * 1024);
                GLD16(vg + voff[j], vd + j * 1024);
            }
        }
        const char* kb = lds + buf * 32768;
        const char* vb = lds + buf * 32768 + 16384;

        // QK^T: S[m=li-ish rows][n] over c=256; two accumulator chains
        f32x16 Sa, Sb;
#pragma unroll
        for (int r = 0; r < 16; ++r) { Sa[r] = 0.f; Sb[r] = 0.f; }
#pragma unroll
        for (int cs = 0; cs < 16; cs += 2) {
            bf16x8 a0 = *(const bf16x8*)(kb + li * 512 + (((cs * 2 + hi) ^ li) << 4));
            Sa = mfma32(a0, qf[cs], Sa);
            bf16x8 a1 = *(const bf16x8*)(kb + li * 512 + ((((cs + 1) * 2 + hi) ^ li) << 4));
            Sb = mfma32(a1, qf[cs + 1], Sb);
        }
        f32x16 S = Sa + Sb;                       // scaled: kT carries QSCALE^2 total

        // online softmax (exp2 domain); lane-local n, m spans regs + lane^32
        float tmax = S[0];
#pragma unroll
        for (int r = 1; r < 16; ++r) tmax = fmaxf(tmax, S[r]);
        tmax = fmaxf(tmax, __shfl_xor(tmax, 32, 64));
        if (__any(tmax > M)) {                    // T13: skip rescale when max holds
            float newM = fmaxf(M, tmax);
            float alpha = exp2f(M - newM);
            M = newM;
            L *= alpha;
#pragma unroll
            for (int vc = 0; vc < 8; ++vc) ctx[vc] = ctx[vc] * alpha;
        }
        float tsum = 0.f;
#pragma unroll
        for (int r = 0; r < 16; ++r) {
            float p = exp2f(S[r] - M);
            S[r] = p;
            tsum += p;
        }
        tsum += __shfl_xor(tsum, 32, 64);
        L += tsum;

        // T12: pack P rows to bf16 B-frags via cvt_pk + permlane32_swap
        unsigned c0 = cvtpk(S[0], S[1]),  c1 = cvtpk(S[2], S[3]);
        unsigned c2 = cvtpk(S[4], S[5]),  c3 = cvtpk(S[6], S[7]);
        unsigned c4 = cvtpk(S[8], S[9]),  c5 = cvtpk(S[10], S[11]);
        unsigned c6 = cvtpk(S[12], S[13]), c7 = cvtpk(S[14], S[15]);
        auto r0 = __builtin_amdgcn_permlane32_swap(c0, c2, false, false);
        auto r1 = __builtin_amdgcn_permlane32_swap(c1, c3, false, false);
        auto r2 = __builtin_amdgcn_permlane32_swap(c4, c6, false, false);
        auto r3 = __builtin_amdgcn_permlane32_swap(c5, c7, false, false);
        union U8 { unsigned u[4]; bf16x8 v; } B1, B2;
        B1.u[0] = r0[0]; B1.u[1] = r1[0]; B1.u[2] = r0[1]; B1.u[3] = r1[1];
        B2.u[0] = r2[0]; B2.u[1] = r3[0]; B2.u[2] = r2[1]; B2.u[3] = r3[1];

        // PV: ctx[v][n] += sum_m V[v][m] P[m][n]; A from [mg][v][8] planes
#pragma unroll
        for (int vc = 0; vc < 8; ++vc) {
            bf16x8 va = *(const bf16x8*)(vb + hi * 4096 + (vc * 32 + li) * 16);
            ctx[vc] = mfma32(va, B1.v, ctx[vc]);
        }
#pragma unroll
        for (int vc = 0; vc < 8; ++vc) {
            bf16x8 va = *(const bf16x8*)(vb + (2 + hi) * 4096 + (vc * 32 + li) * 16);
            ctx[vc] = mfma32(va, B2.v, ctx[vc]);
        }
        if (it + 1 < Nn / 32) __syncthreads();
    }

    // epilogue: normalize, store ctxT[b,n,v] bf16 (lane col n, rows v per reg)
    float inv = 1.0f / L;
    bf16* crow = ctxT + ((size_t)(b * Nn + n)) * Vv;
#pragma unroll
    for (int vc = 0; vc < 8; ++vc) {
#pragma unroll
        for (int rq = 0; rq < 4; ++rq) {
            bf16x4 o;
#pragma unroll
            for (int r = 0; r < 4; ++r) o[r] = (bf16)(ctx[vc][rq * 4 + r] * inv);
            *(bf16x4*)(crow + vc * 32 + rq * 8 + hi * 4) = o;
        }
    }
}

// ---------------- out: wW @ ctx + bW, f32 -----------------------------------
__global__ __launch_bounds__(256) void out_kernel(
        const bf16* __restrict__ ctxT, const bf16* __restrict__ wWb,
        const float* __restrict__ bW, float* __restrict__ out) {
    int b = blockIdx.y;
    int w = threadIdx.x >> 6, l = threadIdx.x & 63, g = l >> 4, i = l & 15;
    int n = blockIdx.x * 64 + w * 16 + i;
    const bf16* crow = ctxT + ((size_t)(b * Nn + n)) * Vv;
    bf16x8 bfr[8];
#pragma unroll
    for (int kk = 0; kk < 8; ++kk) bfr[kk] = *(const bf16x8*)(crow + g * 8 + kk * 32);
    for (int oc = 0; oc < 32; ++oc) {
        f32x4 acc = {0.f, 0.f, 0.f, 0.f};
        const bf16* arow = wWb + (size_t)(oc * 16 + i) * Vv;
#pragma unroll
        for (int kk = 0; kk < 8; ++kk)
            acc = mfma16(*(const bf16x8*)(arow + g * 8 + kk * 32), bfr[kk], acc);
        int o0 = oc * 16 + g * 4;
#pragma unroll
        for (int r = 0; r < 4; ++r)
            out[((size_t)(b * Oo + o0 + r)) * Nn + n] = acc[r] + bW[o0 + r];
    }
}

// ---------------------------------------------------------------------------
extern "C" void kernel_launch(void* const* d_in, const int* in_sizes, int n_in,
                              void* d_out, int out_size, void* d_ws, size_t ws_size,
                              hipStream_t stream) {
    const float* x     = (const float*)d_in[0];
    const float* wv    = (const float*)d_in[1];
    const float* bv    = (const float*)d_in[2];
    const float* wk    = (const float*)d_in[3];
    const float* bk    = (const float*)d_in[4];
    const float* gamma = (const float*)d_in[5];
    const float* beta  = (const float*)d_in[6];
    const float* rmean = (const float*)d_in[7];
    const float* rvar  = (const float*)d_in[8];
    const float* wW    = (const float*)d_in[9];
    const float* bW    = (const float*)d_in[10];
    float* out = (float*)d_out;

    char* ws = (char*)d_ws;
    bf16*  xT     = (bf16*)(ws + 0);          // 32 MiB
    bf16*  kTp    = (bf16*)(ws + 33554432);   // 16 MiB
    bf16*  valp   = (bf16*)(ws + 50331648);   // 16 MiB
    bf16*  ctxT   = (bf16*)(ws + 67108864);   // 16 MiB
    bf16*  wkv    = (bf16*)(ws + 83886080);   // 512 KiB
    bf16*  wWb    = (bf16*)(ws + 84410368);   // 256 KiB
    float* shift2 = (float*)(ws + 84672512);  // 1 KiB

    prep_kernel<<<dim3(1537), dim3(256), 0, stream>>>(wk, wv, wW, bk, gamma, beta,
                                                      rmean, rvar, wkv, wWb, shift2);
    transpose_kernel<<<dim3(64, 16, 8), dim3(256), 0, stream>>>(x, xT);
    proj_kernel<<<dim3(64, 8), dim3(256), 0, stream>>>(xT, wkv, shift2, bv, kTp, valp);
    flash_kernel<<<dim3(8, 64), dim3(128), 0, stream>>>(kTp, valp, ctxT);
    out_kernel<<<dim3(64, 8), dim3(256), 0, stream>>>(ctxT, wWb, bW, out);
}

// Round 3
// 366.650 us; speedup vs baseline: 1.4809x; 1.2895x over previous
//
#include <hip/hip_runtime.h>
#include <hip/hip_bf16.h>
#include <stdint.h>

// ---------------------------------------------------------------------------
// BaseAttentionBlock: x[8,512,64,64] -> out[8,512,64,64]
//   value = wv@x + bv; k = relu(BN(wk@x+bk)); sim = softmax(kT k /16);
//   ctx = sim @ value^T; out = wW@ctx + bW
// Flash attention on mfma_f32_32x32x16_bf16, q=32/wave, 4-wave blocks,
// KV-split x2 (partials combined in out_kernel). Counted vmcnt pipeline.
// kT pre-scaled by sqrt(1/16 * log2(e)) so softmax runs in exp2 domain.
// ---------------------------------------------------------------------------

typedef __bf16 bf16;
typedef bf16 bf16x4 __attribute__((ext_vector_type(4)));
typedef bf16 bf16x8 __attribute__((ext_vector_type(8)));
typedef float f32x4 __attribute__((ext_vector_type(4)));
typedef float f32x16 __attribute__((ext_vector_type(16)));

#define Bb 8
#define Cc 512
#define Nn 4096
#define Kc 256
#define Vv 256
#define Oo 512
#define BN_EPS 1e-5f
#define QSCALE 0.300280601f   // sqrt(0.0625 * log2(e)); applied to kT per side

static __device__ __forceinline__ f32x4 mfma16(bf16x8 a, bf16x8 b, f32x4 c) {
    return __builtin_amdgcn_mfma_f32_16x16x32_bf16(a, b, c, 0, 0, 0);
}
static __device__ __forceinline__ f32x16 mfma32(bf16x8 a, bf16x8 b, f32x16 c) {
    return __builtin_amdgcn_mfma_f32_32x32x16_bf16(a, b, c, 0, 0, 0);
}
static __device__ __forceinline__ unsigned cvtpk(float lo, float hi) {
    unsigned r;
    asm("v_cvt_pk_bf16_f32 %0, %1, %2" : "=v"(r) : "v"(lo), "v"(hi));
    return r;
}
#define GLD16(gp, lp) __builtin_amdgcn_global_load_lds( \
    (const __attribute__((address_space(1))) unsigned int*)(gp), \
    (__attribute__((address_space(3))) unsigned int*)(lp), 16, 0, 0)

// ---------------- prep: fold BN into wk, cast weights to bf16 ---------------
__global__ __launch_bounds__(256) void prep_kernel(
        const float* __restrict__ wk, const float* __restrict__ wv,
        const float* __restrict__ wW, const float* __restrict__ bk,
        const float* __restrict__ gamma, const float* __restrict__ beta,
        const float* __restrict__ rmean, const float* __restrict__ rvar,
        bf16* __restrict__ wkv, bf16* __restrict__ wWb, float* __restrict__ shift2) {
    int idx = blockIdx.x * 256 + threadIdx.x;
    if (idx < 131072) {                      // wk rows 0..255 with BN scale folded
        int kc = idx >> 9;
        float sc = gamma[kc] * rsqrtf(rvar[kc] + BN_EPS);
        wkv[idx] = (bf16)(wk[idx] * sc);
    } else if (idx < 262144) {               // wv rows 256..511
        wkv[idx] = (bf16)(wv[idx - 131072]);
    } else if (idx < 393216) {
        int j = idx - 262144;
        wWb[j] = (bf16)(wW[j]);
    } else if (idx < 393472) {
        int kc = idx - 393216;
        float sc = gamma[kc] * rsqrtf(rvar[kc] + BN_EPS);
        shift2[kc] = (bk[kc] - rmean[kc]) * sc + beta[kc];
    }
}

// ---------------- transpose: x[b,c,n] f32 -> xT[b,n,c] bf16 -----------------
__global__ __launch_bounds__(256) void transpose_kernel(
        const float* __restrict__ x, bf16* __restrict__ xT) {
    int b = blockIdx.z, c0 = blockIdx.y * 32, n0 = blockIdx.x * 64;
    __shared__ float lds[32][65];
    int t = threadIdx.x;
    int r = t >> 3, s = t & 7;
    const float* src = x + ((size_t)(b * Cc + c0 + r)) * Nn + n0 + s * 8;
    float4 v0 = *(const float4*)src;
    float4 v1 = *(const float4*)(src + 4);
    lds[r][s * 8 + 0] = v0.x; lds[r][s * 8 + 1] = v0.y;
    lds[r][s * 8 + 2] = v0.z; lds[r][s * 8 + 3] = v0.w;
    lds[r][s * 8 + 4] = v1.x; lds[r][s * 8 + 5] = v1.y;
    lds[r][s * 8 + 6] = v1.z; lds[r][s * 8 + 7] = v1.w;
    __syncthreads();
    int wr = t >> 2, part = t & 3;
    bf16x8 o;
#pragma unroll
    for (int j = 0; j < 8; ++j) o[j] = (bf16)lds[part * 8 + j][wr];
    *(bf16x8*)(xT + ((size_t)(b * Nn + n0 + wr)) * Cc + c0 + part * 8) = o;
}

// ------- proj: kT[b,n,kc]=relu(BN(wk@x+bk))*QSCALE, val[b,v,n]=wv@x+bv ------
__global__ __launch_bounds__(256) void proj_kernel(
        const bf16* __restrict__ xT, const bf16* __restrict__ wkv,
        const float* __restrict__ shift2, const float* __restrict__ bv,
        bf16* __restrict__ kT, bf16* __restrict__ val) {
    int b = blockIdx.y;
    int w = threadIdx.x >> 6, l = threadIdx.x & 63, g = l >> 4, i = l & 15;
    int n = blockIdx.x * 64 + w * 16 + i;
    const bf16* xrow = xT + ((size_t)(b * Nn + n)) * Cc;
    bf16x8 bf[16];
#pragma unroll
    for (int kk = 0; kk < 16; ++kk) bf[kk] = *(const bf16x8*)(xrow + g * 8 + kk * 32);
    for (int oc = 0; oc < 32; ++oc) {
        f32x4 acc = {0.f, 0.f, 0.f, 0.f};
        const bf16* arow = wkv + (size_t)(oc * 16 + i) * Cc;
#pragma unroll
        for (int kk = 0; kk < 16; ++kk) {
            bf16x8 a = *(const bf16x8*)(arow + g * 8 + kk * 32);
            acc = mfma16(a, bf[kk], acc);
        }
        if (oc < 16) {                       // key channels: BN shift + relu + qscale
            int kc0 = oc * 16 + g * 4;
            bf16x4 ov;
#pragma unroll
            for (int r2 = 0; r2 < 4; ++r2) {
                float v = acc[r2] + shift2[kc0 + r2];
                ov[r2] = (bf16)(fmaxf(v, 0.f) * QSCALE);
            }
            *(bf16x4*)(kT + ((size_t)(b * Nn + n)) * Kc + kc0) = ov;
        } else {                             // value channels
            int vc0 = (oc - 16) * 16 + g * 4;
#pragma unroll
            for (int r2 = 0; r2 < 4; ++r2) {
                float v = acc[r2] + bv[vc0 + r2];
                val[((size_t)(b * Vv + vc0 + r2)) * Nn + n] = (bf16)v;
            }
        }
    }
}

// ---------------- flash attention (KV-split partials) -----------------------
// 256 threads = 4 waves, each wave 32 q-rows (128 q/block). KV tile M=32,
// double-buffered, counted vmcnt(8) (never drained in-loop). grid (8,32,2):
// x=batch (XCD affinity), y=q-tile, z=KV split. Emits un-normalized bf16
// partial ctx + (M,L) per q-row.
__global__ __launch_bounds__(256, 2) void flash_kernel(
        const bf16* __restrict__ kT, const bf16* __restrict__ val,
        bf16* __restrict__ ctxP, float* __restrict__ ml) {
    __shared__ __align__(16) char lds[65536];     // 2 x (16KB K + 16KB V)
    const int t = threadIdx.x;
    const int b = blockIdx.x;
    const int s = blockIdx.z;
    const int w = t >> 6, l = t & 63, li = l & 31, hi = l >> 5;
    const int n = blockIdx.y * 128 + w * 32 + li;
    const int m0 = s * (Nn / 2);
    const int NT = (Nn / 2) / 32;                 // 64 KV tiles per split

    const bf16* kTb  = kT  + (size_t)b * Nn * Kc;
    const bf16* valb = val + (size_t)b * Vv * Nn;

    // Q fragments (B operand): Q[col n][k = cs*16 + hi*8 + j]
    const bf16* qrow = kTb + (size_t)n * Kc;
    bf16x8 qf[16];
#pragma unroll
    for (int cs = 0; cs < 16; ++cs) qf[cs] = *(const bf16x8*)(qrow + cs * 16 + hi * 8);

    // K staging source offsets (swizzle pre-applied): row r, stored slot t&31
    int koff[4];
#pragma unroll
    for (int j = 0; j < 4; ++j) {
        int r = j * 8 + (t >> 5);
        koff[j] = r * Kc + ((t & 31) ^ r) * 8;
    }
    char* kdst = lds + w * 1024;                  // wave-uniform GLD bases
    char* vdst = lds + 16384 + w * 1024;

    f32x16 ctx[8];
#pragma unroll
    for (int vc = 0; vc < 8; ++vc)
#pragma unroll
        for (int r = 0; r < 16; ++r) ctx[vc][r] = 0.f;
    float M = -1.0e30f, L = 0.f;

    auto STAGE = [&](int tile, int bb) {
        const bf16* kg = kTb + (size_t)(m0 + tile * 32) * Kc;
        const bf16* vg = valb + (size_t)t * Nn + (m0 + tile * 32);
#pragma unroll
        for (int j = 0; j < 4; ++j) GLD16(kg + koff[j], kdst + bb * 32768 + j * 4096);
#pragma unroll
        for (int j = 0; j < 4; ++j) GLD16(vg + j * 8, vdst + bb * 32768 + j * 4096);
    };

    STAGE(0, 0);
    for (int it = 0; it < NT; ++it) {
        const int bb = it & 1;
        if (it + 1 < NT) {
            STAGE(it + 1, bb ^ 1);
            asm volatile("s_waitcnt vmcnt(8)" ::: "memory");   // tile it landed
        } else {
            asm volatile("s_waitcnt vmcnt(0)" ::: "memory");
        }
        __builtin_amdgcn_s_barrier();
        __builtin_amdgcn_sched_barrier(0);
        const char* kb = lds + bb * 32768;
        const char* vb = kb + 16384;

        // QK^T: S[m][n] over c=256 (A = K from LDS, B = Q regs)
        f32x16 S;
#pragma unroll
        for (int r = 0; r < 16; ++r) S[r] = 0.f;
        __builtin_amdgcn_s_setprio(1);
#pragma unroll
        for (int cs = 0; cs < 16; ++cs) {
            bf16x8 a0 = *(const bf16x8*)(kb + li * 512 + (((cs * 2 + hi) ^ li) << 4));
            S = mfma32(a0, qf[cs], S);
        }
        __builtin_amdgcn_s_setprio(0);

        // online softmax (exp2 domain), T13 defer-max threshold 8
        float tmax = S[0];
#pragma unroll
        for (int r = 1; r < 16; ++r) tmax = fmaxf(tmax, S[r]);
        tmax = fmaxf(tmax, __shfl_xor(tmax, 32, 64));
        if (__any(tmax > M + 8.f)) {
            float newM = fmaxf(M, tmax);
            float alpha = exp2f(M - newM);
            M = newM;
            L *= alpha;
#pragma unroll
            for (int vc = 0; vc < 8; ++vc) ctx[vc] = ctx[vc] * alpha;
        }
        float tsum = 0.f;
#pragma unroll
        for (int r = 0; r < 16; ++r) {
            float p = exp2f(S[r] - M);
            S[r] = p;
            tsum += p;
        }
        tsum += __shfl_xor(tsum, 32, 64);
        L += tsum;

        // T12: pack P rows to bf16 B-frags via cvt_pk + permlane32_swap
        unsigned c0 = cvtpk(S[0], S[1]),  c1 = cvtpk(S[2], S[3]);
        unsigned c2 = cvtpk(S[4], S[5]),  c3 = cvtpk(S[6], S[7]);
        unsigned c4 = cvtpk(S[8], S[9]),  c5 = cvtpk(S[10], S[11]);
        unsigned c6 = cvtpk(S[12], S[13]), c7 = cvtpk(S[14], S[15]);
        auto r0 = __builtin_amdgcn_permlane32_swap(c0, c2, false, false);
        auto r1 = __builtin_amdgcn_permlane32_swap(c1, c3, false, false);
        auto r2 = __builtin_amdgcn_permlane32_swap(c4, c6, false, false);
        auto r3 = __builtin_amdgcn_permlane32_swap(c5, c7, false, false);
        union U8 { unsigned u[4]; bf16x8 v; } B1, B2;
        B1.u[0] = r0[0]; B1.u[1] = r1[0]; B1.u[2] = r0[1]; B1.u[3] = r1[1];
        B2.u[0] = r2[0]; B2.u[1] = r3[0]; B2.u[2] = r2[1]; B2.u[3] = r3[1];

        // PV: ctx[v][n] += sum_m V[v][m] P[m][n]; A from [mg][v][8] planes
        __builtin_amdgcn_s_setprio(1);
#pragma unroll
        for (int vc = 0; vc < 8; ++vc) {
            bf16x8 va = *(const bf16x8*)(vb + hi * 4096 + (vc * 32 + li) * 16);
            ctx[vc] = mfma32(va, B1.v, ctx[vc]);
        }
#pragma unroll
        for (int vc = 0; vc < 8; ++vc) {
            bf16x8 va = *(const bf16x8*)(vb + (2 + hi) * 4096 + (vc * 32 + li) * 16);
            ctx[vc] = mfma32(va, B2.v, ctx[vc]);
        }
        __builtin_amdgcn_s_setprio(0);
        if (it + 1 < NT) {
            __builtin_amdgcn_sched_barrier(0);
            __builtin_amdgcn_s_barrier();    // all reads of bb done -> restage ok
        }
    }

    // epilogue: store UN-normalized partial ctx (bf16) + (M,L)
    size_t idx = (size_t)(s * Bb + b) * Nn + n;
    bf16* crow = ctxP + idx * Vv;
#pragma unroll
    for (int vc = 0; vc < 8; ++vc) {
#pragma unroll
        for (int rq = 0; rq < 4; ++rq) {
            bf16x4 o;
#pragma unroll
            for (int r = 0; r < 4; ++r) o[r] = (bf16)ctx[vc][rq * 4 + r];
            *(bf16x4*)(crow + vc * 32 + rq * 8 + hi * 4) = o;
        }
    }
    if (hi == 0) {
        float2 v; v.x = M; v.y = L;
        *(float2*)(ml + idx * 2) = v;
    }
}

// ------- out: combine KV-split partials, then wW @ ctx + bW, f32 ------------
__global__ __launch_bounds__(256) void out_kernel(
        const bf16* __restrict__ ctxP, const float* __restrict__ ml,
        const bf16* __restrict__ wWb, const float* __restrict__ bW,
        float* __restrict__ out) {
    int b = blockIdx.y;
    int w = threadIdx.x >> 6, l = threadIdx.x & 63, g = l >> 4, i = l & 15;
    int n = blockIdx.x * 64 + w * 16 + i;
    size_t iA = (size_t)b * Nn + n;
    size_t iB = (size_t)(Bb + b) * Nn + n;
    const bf16* ca = ctxP + iA * Vv;
    const bf16* cb = ctxP + iB * Vv;
    float MA = ml[iA * 2], LA = ml[iA * 2 + 1];
    float MB = ml[iB * 2], LB = ml[iB * 2 + 1];
    float Mx = fmaxf(MA, MB);
    float wA = exp2f(MA - Mx), wB = exp2f(MB - Mx);
    float inv = 1.f / (LA * wA + LB * wB);
    float sA = wA * inv, sB = wB * inv;
    bf16x8 bfr[8];
#pragma unroll
    for (int kk = 0; kk < 8; ++kk) {
        bf16x8 fa = *(const bf16x8*)(ca + g * 8 + kk * 32);
        bf16x8 fb = *(const bf16x8*)(cb + g * 8 + kk * 32);
        bf16x8 o;
#pragma unroll
        for (int j = 0; j < 8; ++j)
            o[j] = (bf16)(sA * (float)fa[j] + sB * (float)fb[j]);
        bfr[kk] = o;
    }
    for (int oc = 0; oc < 32; ++oc) {
        f32x4 acc = {0.f, 0.f, 0.f, 0.f};
        const bf16* arow = wWb + (size_t)(oc * 16 + i) * Vv;
#pragma unroll
        for (int kk = 0; kk < 8; ++kk)
            acc = mfma16(*(const bf16x8*)(arow + g * 8 + kk * 32), bfr[kk], acc);
        int o0 = oc * 16 + g * 4;
#pragma unroll
        for (int r = 0; r < 4; ++r)
            out[((size_t)(b * Oo + o0 + r)) * Nn + n] = acc[r] + bW[o0 + r];
    }
}

// ---------------------------------------------------------------------------
extern "C" void kernel_launch(void* const* d_in, const int* in_sizes, int n_in,
                              void* d_out, int out_size, void* d_ws, size_t ws_size,
                              hipStream_t stream) {
    const float* x     = (const float*)d_in[0];
    const float* wv    = (const float*)d_in[1];
    const float* bv    = (const float*)d_in[2];
    const float* wk    = (const float*)d_in[3];
    const float* bk    = (const float*)d_in[4];
    const float* gamma = (const float*)d_in[5];
    const float* beta  = (const float*)d_in[6];
    const float* rmean = (const float*)d_in[7];
    const float* rvar  = (const float*)d_in[8];
    const float* wW    = (const float*)d_in[9];
    const float* bW    = (const float*)d_in[10];
    float* out = (float*)d_out;

    char* ws = (char*)d_ws;
    // ctxP overlays xT: xT dead after proj_kernel, flash writes ctxP after.
    bf16*  xT     = (bf16*)(ws + 0);          // 32 MiB (transpose -> proj)
    bf16*  ctxP   = (bf16*)(ws + 0);          // 32 MiB (flash -> out), 2 splits
    bf16*  kTp    = (bf16*)(ws + 33554432);   // 16 MiB
    bf16*  valp   = (bf16*)(ws + 50331648);   // 16 MiB
    bf16*  wkv    = (bf16*)(ws + 67108864);   // 512 KiB
    bf16*  wWb    = (bf16*)(ws + 67633152);   // 256 KiB
    float* shift2 = (float*)(ws + 67895296);  // 1 KiB
    float* ml     = (float*)(ws + 68157440);  // 512 KiB (2*8*4096 * {M,L})

    prep_kernel<<<dim3(1537), dim3(256), 0, stream>>>(wk, wv, wW, bk, gamma, beta,
                                                      rmean, rvar, wkv, wWb, shift2);
    transpose_kernel<<<dim3(64, 16, 8), dim3(256), 0, stream>>>(x, xT);
    proj_kernel<<<dim3(64, 8), dim3(256), 0, stream>>>(xT, wkv, shift2, bv, kTp, valp);
    flash_kernel<<<dim3(8, 32, 2), dim3(256), 0, stream>>>(kTp, valp, ctxP, ml);
    out_kernel<<<dim3(64, 8), dim3(256), 0, stream>>>(ctxP, ml, wWb, bW, out);
}

// Round 5
// 292.797 us; speedup vs baseline: 1.8544x; 1.2522x over previous
//
#include <hip/hip_runtime.h>
#include <hip/hip_bf16.h>
#include <stdint.h>

// ---------------------------------------------------------------------------
// BaseAttentionBlock: x[8,512,64,64] -> out[8,512,64,64]
//   value = wv@x + bv; k = relu(BN(wk@x+bk)); sim = softmax(kT k /16);
//   ctx = sim @ value^T; out = wW@ctx + bW
// Flash attention on mfma_f32_32x32x16_bf16, q=32/wave, 4-wave blocks,
// KV-split x2 (partials combined in out_kernel). Counted vmcnt pipeline.
// kT pre-scaled by sqrt(1/16 * log2(e)) so softmax runs in exp2 domain.
// proj/out: register-resident activations, weights streamed through L1/L2.
// ---------------------------------------------------------------------------

typedef __bf16 bf16;
typedef bf16 bf16x4 __attribute__((ext_vector_type(4)));
typedef bf16 bf16x8 __attribute__((ext_vector_type(8)));
typedef float f32x4 __attribute__((ext_vector_type(4)));
typedef float f32x16 __attribute__((ext_vector_type(16)));

#define Bb 8
#define Cc 512
#define Nn 4096
#define Kc 256
#define Vv 256
#define Oo 512
#define BN_EPS 1e-5f
#define QSCALE 0.300280601f   // sqrt(0.0625 * log2(e)); applied to kT per side

static __device__ __forceinline__ f32x16 mfma32(bf16x8 a, bf16x8 b, f32x16 c) {
    return __builtin_amdgcn_mfma_f32_32x32x16_bf16(a, b, c, 0, 0, 0);
}
static __device__ __forceinline__ unsigned cvtpk(float lo, float hi) {
    unsigned r;
    asm("v_cvt_pk_bf16_f32 %0, %1, %2" : "=v"(r) : "v"(lo), "v"(hi));
    return r;
}
#define GLD16(gp, lp) __builtin_amdgcn_global_load_lds( \
    (const __attribute__((address_space(1))) unsigned int*)(gp), \
    (__attribute__((address_space(3))) unsigned int*)(lp), 16, 0, 0)

// ---------------- prep: fold BN into wk, cast weights to bf16 ---------------
__global__ __launch_bounds__(256) void prep_kernel(
        const float* __restrict__ wk, const float* __restrict__ wv,
        const float* __restrict__ wW, const float* __restrict__ bk,
        const float* __restrict__ gamma, const float* __restrict__ beta,
        const float* __restrict__ rmean, const float* __restrict__ rvar,
        bf16* __restrict__ wkv, bf16* __restrict__ wWb, float* __restrict__ shift2) {
    int idx = blockIdx.x * 256 + threadIdx.x;
    if (idx < 131072) {                      // wk rows 0..255 with BN scale folded
        int kc = idx >> 9;
        float sc = gamma[kc] * rsqrtf(rvar[kc] + BN_EPS);
        wkv[idx] = (bf16)(wk[idx] * sc);
    } else if (idx < 262144) {               // wv rows 256..511
        wkv[idx] = (bf16)(wv[idx - 131072]);
    } else if (idx < 393216) {
        int j = idx - 262144;
        wWb[j] = (bf16)(wW[j]);
    } else if (idx < 393472) {
        int kc = idx - 393216;
        float sc = gamma[kc] * rsqrtf(rvar[kc] + BN_EPS);
        shift2[kc] = (bk[kc] - rmean[kc]) * sc + beta[kc];
    }
}

// ---------------- transpose: x[b,c,n] f32 -> xT[b,n,c] bf16 -----------------
__global__ __launch_bounds__(256) void transpose_kernel(
        const float* __restrict__ x, bf16* __restrict__ xT) {
    int b = blockIdx.z, c0 = blockIdx.y * 32, n0 = blockIdx.x * 64;
    __shared__ float lds[32][65];
    int t = threadIdx.x;
    int r = t >> 3, s = t & 7;
    const float* src = x + ((size_t)(b * Cc + c0 + r)) * Nn + n0 + s * 8;
    float4 v0 = *(const float4*)src;
    float4 v1 = *(const float4*)(src + 4);
    lds[r][s * 8 + 0] = v0.x; lds[r][s * 8 + 1] = v0.y;
    lds[r][s * 8 + 2] = v0.z; lds[r][s * 8 + 3] = v0.w;
    lds[r][s * 8 + 4] = v1.x; lds[r][s * 8 + 5] = v1.y;
    lds[r][s * 8 + 6] = v1.z; lds[r][s * 8 + 7] = v1.w;
    __syncthreads();
    int wr = t >> 2, part = t & 3;
    bf16x8 o;
#pragma unroll
    for (int j = 0; j < 8; ++j) o[j] = (bf16)lds[part * 8 + j][wr];
    *(bf16x8*)(xT + ((size_t)(b * Nn + n0 + wr)) * Cc + c0 + part * 8) = o;
}

// ------- proj: kT[b,n,kc]=relu(BN(wk@x+bk))*QSCALE, val[b,v,n]=wv@x+bv ------
// 512 blocks; block = (b, 64-n tile). Wave w: nsub=w&1 (32 n), ochalf=w>>1
// (256 oc). x-rows register-resident (32 bf16x8); weights streamed from L1/L2.
__global__ __launch_bounds__(256, 2) void proj_kernel(
        const bf16* __restrict__ xT, const bf16* __restrict__ wkv,
        const float* __restrict__ shift2, const float* __restrict__ bv,
        bf16* __restrict__ kT, bf16* __restrict__ val) {
    int tile = blockIdx.x;
    int b = tile >> 6, n0 = (tile & 63) * 64;
    int t = threadIdx.x, w = t >> 6, l = t & 63, li = l & 31, hi = l >> 5;
    int nsub = w & 1, ochalf = w >> 1;
    int n = n0 + nsub * 32 + li;

    const bf16* xrow = xT + ((size_t)(b * Nn + n)) * Cc + hi * 8;
    bf16x8 bfr[32];
#pragma unroll
    for (int cs = 0; cs < 32; ++cs) bfr[cs] = *(const bf16x8*)(xrow + cs * 16);

    f32x16 Z;
#pragma unroll
    for (int r = 0; r < 16; ++r) Z[r] = 0.f;

    for (int ocb = 0; ocb < 8; ++ocb) {
        int ocbase = ochalf * 256 + ocb * 32;
        const bf16* arow = wkv + (size_t)(ocbase + li) * Cc + hi * 8;
        f32x16 acc = mfma32(*(const bf16x8*)(arow), bfr[0], Z);
#pragma unroll
        for (int cs = 1; cs < 32; ++cs)
            acc = mfma32(*(const bf16x8*)(arow + cs * 16), bfr[cs], acc);
        // D: col = li (n), row = (reg&3) + 8*(reg>>2) + 4*hi (oc within 32)
        if (ocbase < 256) {                  // key channels: BN + relu + qscale
#pragma unroll
            for (int rq = 0; rq < 4; ++rq) {
                int kc0 = ocbase + rq * 8 + hi * 4;
                bf16x4 o;
#pragma unroll
                for (int r = 0; r < 4; ++r) {
                    float v = acc[rq * 4 + r] + shift2[kc0 + r];
                    o[r] = (bf16)(fmaxf(v, 0.f) * QSCALE);
                }
                *(bf16x4*)(kT + ((size_t)(b * Nn + n)) * Kc + kc0) = o;
            }
        } else {                             // value channels -> val[v][n]
#pragma unroll
            for (int rq = 0; rq < 4; ++rq)
#pragma unroll
                for (int r = 0; r < 4; ++r) {
                    int vc = ocbase - 256 + rq * 8 + hi * 4 + r;
                    val[((size_t)(b * Vv + vc)) * Nn + n] = (bf16)(acc[rq * 4 + r] + bv[vc]);
                }
        }
    }
}

// ---------------- flash attention (KV-split partials) -----------------------
// 256 threads = 4 waves, each wave 32 q-rows (128 q/block). KV tile M=32,
// double-buffered, counted vmcnt(8). grid (8,32,2): x=batch (XCD affinity),
// y=q-tile, z=KV split. Emits un-normalized bf16 partial ctx + (M,L).
__global__ __launch_bounds__(256, 2) void flash_kernel(
        const bf16* __restrict__ kT, const bf16* __restrict__ val,
        bf16* __restrict__ ctxP, float* __restrict__ ml) {
    __shared__ __align__(16) char lds[65536];     // 2 x (16KB K + 16KB V)
    const int t = threadIdx.x;
    const int b = blockIdx.x;
    const int s = blockIdx.z;
    const int w = t >> 6, l = t & 63, li = l & 31, hi = l >> 5;
    const int n = blockIdx.y * 128 + w * 32 + li;
    const int m0 = s * (Nn / 2);
    const int NT = (Nn / 2) / 32;                 // 64 KV tiles per split

    const bf16* kTb  = kT  + (size_t)b * Nn * Kc;
    const bf16* valb = val + (size_t)b * Vv * Nn;

    // Q fragments (B operand): Q[col n][k = cs*16 + hi*8 + j]
    const bf16* qrow = kTb + (size_t)n * Kc;
    bf16x8 qf[16];
#pragma unroll
    for (int cs = 0; cs < 16; ++cs) qf[cs] = *(const bf16x8*)(qrow + cs * 16 + hi * 8);

    // K staging source offsets (swizzle pre-applied): row r, stored slot t&31
    int koff[4];
#pragma unroll
    for (int j = 0; j < 4; ++j) {
        int r = j * 8 + (t >> 5);
        koff[j] = r * Kc + ((t & 31) ^ r) * 8;
    }
    char* kdst = lds + w * 1024;                  // wave-uniform GLD bases
    char* vdst = lds + 16384 + w * 1024;

    // precomputed read addresses:
    //   QK^T: addr = kq ^ (cs<<5)  (bit-identity with stored XOR swizzle)
    //   PV:   addr = pv + plane*8192 + vc*512 (imm-foldable)
    const int kq = li * 512 + ((li ^ hi) << 4);
    const int pv = hi * 4096 + li * 16;

    f32x16 Z;
#pragma unroll
    for (int r = 0; r < 16; ++r) Z[r] = 0.f;
    f32x16 ctx[8];
#pragma unroll
    for (int vc = 0; vc < 8; ++vc) ctx[vc] = Z;
    float M = -1.0e30f, L = 0.f;

    auto STAGE = [&](int tile, int bb) {
        const bf16* kg = kTb + (size_t)(m0 + tile * 32) * Kc;
        const bf16* vg = valb + (size_t)t * Nn + (m0 + tile * 32);
#pragma unroll
        for (int j = 0; j < 4; ++j) GLD16(kg + koff[j], kdst + bb * 32768 + j * 4096);
#pragma unroll
        for (int j = 0; j < 4; ++j) GLD16(vg + j * 8, vdst + bb * 32768 + j * 4096);
    };

    STAGE(0, 0);
    for (int it = 0; it < NT; ++it) {
        const int bb = it & 1;
        if (it + 1 < NT) {
            STAGE(it + 1, bb ^ 1);
            asm volatile("s_waitcnt vmcnt(8)" ::: "memory");   // tile it landed
        } else {
            asm volatile("s_waitcnt vmcnt(0)" ::: "memory");
        }
        __builtin_amdgcn_s_barrier();
        __builtin_amdgcn_sched_barrier(0);
        const char* kb = lds + bb * 32768;
        const char* vb = kb + 16384;

        // QK^T: S[m][n] over c=256 (A = K from LDS, B = Q regs)
        __builtin_amdgcn_s_setprio(1);
        f32x16 S = mfma32(*(const bf16x8*)(kb + kq), qf[0], Z);
#pragma unroll
        for (int cs = 1; cs < 16; ++cs) {
            bf16x8 a0 = *(const bf16x8*)(kb + (kq ^ (cs << 5)));
            S = mfma32(a0, qf[cs], S);
        }
        __builtin_amdgcn_s_setprio(0);

        // online softmax (exp2 domain), T13 defer-max threshold 8; tree max
        float m0a = fmaxf(fmaxf(S[0], S[1]), fmaxf(S[2], S[3]));
        float m0b = fmaxf(fmaxf(S[4], S[5]), fmaxf(S[6], S[7]));
        float m0c = fmaxf(fmaxf(S[8], S[9]), fmaxf(S[10], S[11]));
        float m0d = fmaxf(fmaxf(S[12], S[13]), fmaxf(S[14], S[15]));
        float tmax = fmaxf(fmaxf(m0a, m0b), fmaxf(m0c, m0d));
        tmax = fmaxf(tmax, __shfl_xor(tmax, 32, 64));
        if (__any(tmax > M + 8.f)) {
            float newM = fmaxf(M, tmax);
            float alpha = exp2f(M - newM);
            M = newM;
            L *= alpha;
#pragma unroll
            for (int vc = 0; vc < 8; ++vc) ctx[vc] = ctx[vc] * alpha;
        }
#pragma unroll
        for (int r = 0; r < 16; ++r) S[r] = exp2f(S[r] - M);
        float t0 = (S[0] + S[1]) + (S[2] + S[3]);
        float t1 = (S[4] + S[5]) + (S[6] + S[7]);
        float t2 = (S[8] + S[9]) + (S[10] + S[11]);
        float t3 = (S[12] + S[13]) + (S[14] + S[15]);
        float tsum = (t0 + t1) + (t2 + t3);
        tsum += __shfl_xor(tsum, 32, 64);
        L += tsum;

        // T12: pack P rows to bf16 B-frags via cvt_pk + permlane32_swap
        unsigned c0 = cvtpk(S[0], S[1]),  c1 = cvtpk(S[2], S[3]);
        unsigned c2 = cvtpk(S[4], S[5]),  c3 = cvtpk(S[6], S[7]);
        unsigned c4 = cvtpk(S[8], S[9]),  c5 = cvtpk(S[10], S[11]);
        unsigned c6 = cvtpk(S[12], S[13]), c7 = cvtpk(S[14], S[15]);
        auto r0 = __builtin_amdgcn_permlane32_swap(c0, c2, false, false);
        auto r1 = __builtin_amdgcn_permlane32_swap(c1, c3, false, false);
        auto r2 = __builtin_amdgcn_permlane32_swap(c4, c6, false, false);
        auto r3 = __builtin_amdgcn_permlane32_swap(c5, c7, false, false);
        union U8 { unsigned u[4]; bf16x8 v; } B1, B2;
        B1.u[0] = r0[0]; B1.u[1] = r1[0]; B1.u[2] = r0[1]; B1.u[3] = r1[1];
        B2.u[0] = r2[0]; B2.u[1] = r3[0]; B2.u[2] = r2[1]; B2.u[3] = r3[1];

        // PV: ctx[v][n] += sum_m V[v][m] P[m][n]; A from [mg][v][8] planes
        __builtin_amdgcn_s_setprio(1);
#pragma unroll
        for (int vc = 0; vc < 8; ++vc) {
            bf16x8 va = *(const bf16x8*)(vb + pv + vc * 512);
            ctx[vc] = mfma32(va, B1.v, ctx[vc]);
        }
#pragma unroll
        for (int vc = 0; vc < 8; ++vc) {
            bf16x8 va = *(const bf16x8*)(vb + pv + 8192 + vc * 512);
            ctx[vc] = mfma32(va, B2.v, ctx[vc]);
        }
        __builtin_amdgcn_s_setprio(0);
        if (it + 1 < NT) {
            __builtin_amdgcn_sched_barrier(0);
            __builtin_amdgcn_s_barrier();    // all reads of bb done -> restage ok
        }
    }

    // epilogue: store UN-normalized partial ctx (bf16) + (M,L)
    size_t idx = (size_t)(s * Bb + b) * Nn + n;
    bf16* crow = ctxP + idx * Vv;
#pragma unroll
    for (int vc = 0; vc < 8; ++vc) {
#pragma unroll
        for (int rq = 0; rq < 4; ++rq) {
            bf16x4 o;
#pragma unroll
            for (int r = 0; r < 4; ++r) o[r] = (bf16)ctx[vc][rq * 4 + r];
            *(bf16x4*)(crow + vc * 32 + rq * 8 + hi * 4) = o;
        }
    }
    if (hi == 0) {
        float2 v; v.x = M; v.y = L;
        *(float2*)(ml + idx * 2) = v;
    }
}

// ------- out: combine KV-split partials, then wW @ ctx + bW, f32 ------------
// 512 blocks; block = (b, 64-n tile). Wave w: nsub=w&1 (32 n), ochalf=w>>1.
__global__ __launch_bounds__(256, 2) void out_kernel(
        const bf16* __restrict__ ctxP, const float* __restrict__ ml,
        const bf16* __restrict__ wWb, const float* __restrict__ bW,
        float* __restrict__ out) {
    int tile = blockIdx.x;
    int b = tile >> 6, n0 = (tile & 63) * 64;
    int t = threadIdx.x, w = t >> 6, l = t & 63, li = l & 31, hi = l >> 5;
    int nsub = w & 1, ochalf = w >> 1;
    int n = n0 + nsub * 32 + li;

    size_t iA = (size_t)b * Nn + n;
    size_t iB = (size_t)(Bb + b) * Nn + n;
    const bf16* ca = ctxP + iA * Vv + hi * 8;
    const bf16* cb = ctxP + iB * Vv + hi * 8;
    float MA = ml[iA * 2], LA = ml[iA * 2 + 1];
    float MB = ml[iB * 2], LB = ml[iB * 2 + 1];
    float Mx = fmaxf(MA, MB);
    float wA = exp2f(MA - Mx), wB = exp2f(MB - Mx);
    float inv = 1.f / (LA * wA + LB * wB);
    float sA = wA * inv, sB = wB * inv;

    bf16x8 bfr[16];
#pragma unroll
    for (int cs = 0; cs < 16; ++cs) {
        bf16x8 fa = *(const bf16x8*)(ca + cs * 16);
        bf16x8 fb = *(const bf16x8*)(cb + cs * 16);
        bf16x8 o;
#pragma unroll
        for (int j = 0; j < 8; ++j)
            o[j] = (bf16)(sA * (float)fa[j] + sB * (float)fb[j]);
        bfr[cs] = o;
    }

    f32x16 Z;
#pragma unroll
    for (int r = 0; r < 16; ++r) Z[r] = 0.f;

    for (int ocb = 0; ocb < 8; ++ocb) {
        int ocbase = ochalf * 256 + ocb * 32;
        const bf16* arow = wWb + (size_t)(ocbase + li) * Vv + hi * 8;
        f32x16 acc = mfma32(*(const bf16x8*)(arow), bfr[0], Z);
#pragma unroll
        for (int cs = 1; cs < 16; ++cs)
            acc = mfma32(*(const bf16x8*)(arow + cs * 16), bfr[cs], acc);
#pragma unroll
        for (int rq = 0; rq < 4; ++rq)
#pragma unroll
            for (int r = 0; r < 4; ++r) {
                int oc = ocbase + rq * 8 + hi * 4 + r;
                out[((size_t)(b * Oo + oc)) * Nn + n] = acc[rq * 4 + r] + bW[oc];
            }
    }
}

// ---------------------------------------------------------------------------
extern "C" void kernel_launch(void* const* d_in, const int* in_sizes, int n_in,
                              void* d_out, int out_size, void* d_ws, size_t ws_size,
                              hipStream_t stream) {
    const float* x     = (const float*)d_in[0];
    const float* wv    = (const float*)d_in[1];
    const float* bv    = (const float*)d_in[2];
    const float* wk    = (const float*)d_in[3];
    const float* bk    = (const float*)d_in[4];
    const float* gamma = (const float*)d_in[5];
    const float* beta  = (const float*)d_in[6];
    const float* rmean = (const float*)d_in[7];
    const float* rvar  = (const float*)d_in[8];
    const float* wW    = (const float*)d_in[9];
    const float* bW    = (const float*)d_in[10];
    float* out = (float*)d_out;

    char* ws = (char*)d_ws;
    // ctxP overlays xT: xT dead after proj_kernel, flash writes ctxP after.
    bf16*  xT     = (bf16*)(ws + 0);          // 32 MiB (transpose -> proj)
    bf16*  ctxP   = (bf16*)(ws + 0);          // 32 MiB (flash -> out), 2 splits
    bf16*  kTp    = (bf16*)(ws + 33554432);   // 16 MiB
    bf16*  valp   = (bf16*)(ws + 50331648);   // 16 MiB
    bf16*  wkv    = (bf16*)(ws + 67108864);   // 512 KiB
    bf16*  wWb    = (bf16*)(ws + 67633152);   // 256 KiB
    float* shift2 = (float*)(ws + 67895296);  // 1 KiB
    float* ml     = (float*)(ws + 68157440);  // 512 KiB (2*8*4096 * {M,L})

    prep_kernel<<<dim3(1537), dim3(256), 0, stream>>>(wk, wv, wW, bk, gamma, beta,
                                                      rmean, rvar, wkv, wWb, shift2);
    transpose_kernel<<<dim3(64, 16, 8), dim3(256), 0, stream>>>(x, xT);
    proj_kernel<<<dim3(512), dim3(256), 0, stream>>>(xT, wkv, shift2, bv, kTp, valp);
    flash_kernel<<<dim3(8, 32, 2), dim3(256), 0, stream>>>(kTp, valp, ctxP, ml);
    out_kernel<<<dim3(512), dim3(256), 0, stream>>>(ctxP, ml, wWb, bW, out);
}